// Round 1
// baseline (750.896 us; speedup 1.0000x reference)
//
#include <hip/hip_runtime.h>
#include <cstdint>
#include <cstddef>

#define NAG 32
#define N1C 32
#define N2C 496
#define NF 528
#define HD 64
#define SD 512

__device__ __forceinline__ float elu_f(float x) {
    return x > 0.f ? x : (__expf(x) - 1.f);
}

// ---------------- Kernel 1: shape functions ----------------
// lane -> function f (coalesced writes), loop over 64 rows per block.
#define ROWS1 64
__global__ __launch_bounds__(64) void shape_kernel(
    const float* __restrict__ q,
    const float* __restrict__ w1_1, const float* __restrict__ b1_1,
    const float* __restrict__ w2_1, const float* __restrict__ b2_1,
    const float* __restrict__ w3_1, const float* __restrict__ b3_1,
    const float* __restrict__ w1_2, const float* __restrict__ b1_2,
    const float* __restrict__ w2_2, const float* __restrict__ b2_2,
    const float* __restrict__ w3_2, const float* __restrict__ b3_2,
    float* __restrict__ shape_out, int B)
{
    int f = blockIdx.x * 64 + threadIdx.x;
    bool valid = f < NF;
    int fe = valid ? f : (NF - 1);

    float w1a[8], w1b[8], b1v[8], w2v[32], b2v[4], w3v[4], b3v;
    int pi, pj;
    if (fe < N1C) {
        int n = fe;
        pi = n; pj = n;
        #pragma unroll
        for (int k = 0; k < 8; k++) { w1a[k] = fabsf(w1_1[n*8+k]); w1b[k] = 0.f; b1v[k] = b1_1[n*8+k]; }
        #pragma unroll
        for (int t = 0; t < 32; t++) w2v[t] = fabsf(w2_1[n*32+t]);
        #pragma unroll
        for (int j = 0; j < 4; j++) { b2v[j] = b2_1[n*4+j]; w3v[j] = fabsf(w3_1[n*4+j]); }
        b3v = b3_1[n];
    } else {
        int n = fe - N1C;
        int p = n, i = 0, c = NAG - 1;
        while (p >= c) { p -= c; c--; i++; }
        pi = i; pj = i + 1 + p;
        #pragma unroll
        for (int k = 0; k < 8; k++) { w1a[k] = fabsf(w1_2[n*16+k]); w1b[k] = fabsf(w1_2[n*16+8+k]); b1v[k] = b1_2[n*8+k]; }
        #pragma unroll
        for (int t = 0; t < 32; t++) w2v[t] = fabsf(w2_2[n*32+t]);
        #pragma unroll
        for (int j = 0; j < 4; j++) { b2v[j] = b2_2[n*4+j]; w3v[j] = fabsf(w3_2[n*4+j]); }
        b3v = b3_2[n];
    }

    int row0 = blockIdx.y * ROWS1;
    for (int rr = 0; rr < ROWS1; rr++) {
        int row = row0 + rr;
        float qi = q[row * NAG + pi];
        float qj = q[row * NAG + pj];
        float h1[8];
        #pragma unroll
        for (int k = 0; k < 8; k++) h1[k] = elu_f(w1a[k]*qi + w1b[k]*qj + b1v[k]);
        float h2[4];
        #pragma unroll
        for (int j = 0; j < 4; j++) {
            float a = b2v[j];
            #pragma unroll
            for (int k = 0; k < 8; k++) a += h1[k] * w2v[k*4 + j];
            h2[j] = elu_f(a);
        }
        float fv = b3v;
        #pragma unroll
        for (int j = 0; j < 4; j++) fv += h2[j] * w3v[j];
        if (valid) shape_out[(size_t)row * NF + f] = fv;
    }
}

// ---------------- Kernel 2: encoders + attention + combine ----------------
// 4 waves/block, each wave processes RPW rows. lane -> output column.
// Activation loads are wave-uniform (scalar); weight loads are coalesced
// vector loads reused across RPW rows (cuts L2 weight traffic 8x).
#define RPW 8
__global__ __launch_bounds__(256) void enc_kernel(
    const float* __restrict__ state,
    const float* __restrict__ sem,
    const float* __restrict__ ws_w, const float* __restrict__ ws_b,
    const float* __restrict__ wz_w, const float* __restrict__ wz_b,
    const float* __restrict__ wa1_w, const float* __restrict__ wa1_b,
    const float* __restrict__ wa2_w, const float* __restrict__ wa2_b,
    const float* __restrict__ wb1_w, const float* __restrict__ wb1_b,
    const float* __restrict__ wb2_w, const float* __restrict__ wb2_b,
    const float* __restrict__ shape_out,
    float* __restrict__ q_total,
    float* __restrict__ attn_out,
    int B)
{
    __shared__ float s_comb[4][RPW][128];
    __shared__ float s_h[4][RPW][HD];

    int lane = threadIdx.x & 63;
    int w = threadIdx.x >> 6;
    int r0 = blockIdx.x * (4 * RPW) + w * RPW;
    r0 = __builtin_amdgcn_readfirstlane(r0);

    // ---- phase 1: state -> state_enc (ws) and bias hidden (wb1) ----
    float acc_s[RPW], acc_b[RPW];
    {
        float bs = ws_b[lane], bb = wb1_b[lane];
        #pragma unroll
        for (int r = 0; r < RPW; r++) { acc_s[r] = bs; acc_b[r] = bb; }
    }
    for (int k0 = 0; k0 < SD; k0 += 4) {
        float4 sv[RPW];
        #pragma unroll
        for (int r = 0; r < RPW; r++)
            sv[r] = *(const float4*)&state[(size_t)(r0 + r) * SD + k0];
        #pragma unroll
        for (int kk = 0; kk < 4; kk++) {
            float wv1 = ws_w[(k0 + kk) * HD + lane];
            float wv2 = wb1_w[(k0 + kk) * HD + lane];
            #pragma unroll
            for (int r = 0; r < RPW; r++) {
                float t = ((const float*)&sv[r])[kk];
                acc_s[r] += t * wv1;
                acc_b[r] += t * wv2;
            }
        }
    }
    float qb[RPW];
    {
        float wb2v = wb2_w[lane];
        #pragma unroll
        for (int r = 0; r < RPW; r++) {
            s_comb[w][r][lane] = fmaxf(acc_s[r], 0.f);
            float p = fmaxf(acc_b[r], 0.f) * wb2v;
            #pragma unroll
            for (int off = 1; off < 64; off <<= 1) p += __shfl_xor(p, off, 64);
            qb[r] = p;
        }
    }

    // ---- phase 2: sem -> sem_enc (wz) ----
    float acc_z[RPW];
    {
        float bz = wz_b[lane];
        #pragma unroll
        for (int r = 0; r < RPW; r++) acc_z[r] = bz;
    }
    for (int k0 = 0; k0 < SD; k0 += 4) {
        float4 sv[RPW];
        #pragma unroll
        for (int r = 0; r < RPW; r++)
            sv[r] = *(const float4*)&sem[(size_t)(r0 + r) * SD + k0];
        #pragma unroll
        for (int kk = 0; kk < 4; kk++) {
            float wv1 = wz_w[(k0 + kk) * HD + lane];
            #pragma unroll
            for (int r = 0; r < RPW; r++) {
                float t = ((const float*)&sv[r])[kk];
                acc_z[r] += t * wv1;
            }
        }
    }
    #pragma unroll
    for (int r = 0; r < RPW; r++) s_comb[w][r][64 + lane] = fmaxf(acc_z[r], 0.f);
    __syncthreads();

    // ---- phase 3: hidden = relu(comb @ wa1) ----
    float acc_h[RPW];
    {
        float bh = wa1_b[lane];
        #pragma unroll
        for (int r = 0; r < RPW; r++) acc_h[r] = bh;
    }
    for (int k0 = 0; k0 < 128; k0 += 4) {
        float4 cv[RPW];
        #pragma unroll
        for (int r = 0; r < RPW; r++)
            cv[r] = *(const float4*)&s_comb[w][r][k0];
        #pragma unroll
        for (int kk = 0; kk < 4; kk++) {
            float wv1 = wa1_w[(k0 + kk) * HD + lane];
            #pragma unroll
            for (int r = 0; r < RPW; r++)
                acc_h[r] += ((const float*)&cv[r])[kk] * wv1;
        }
    }
    #pragma unroll
    for (int r = 0; r < RPW; r++) s_h[w][r][lane] = fmaxf(acc_h[r], 0.f);
    __syncthreads();

    // ---- phase 4: logits = hidden @ wa2 + wa2_b ----
    float acc_l[RPW][9];
    int fcl[9];
    #pragma unroll
    for (int c = 0; c < 9; c++) {
        int f = c * 64 + lane;
        fcl[c] = f < NF ? f : (NF - 1);
    }
    #pragma unroll
    for (int c = 0; c < 9; c++) {
        float bv = wa2_b[fcl[c]];
        #pragma unroll
        for (int r = 0; r < RPW; r++) acc_l[r][c] = bv;
    }
    for (int k0 = 0; k0 < HD; k0 += 4) {
        float4 hv[RPW];
        #pragma unroll
        for (int r = 0; r < RPW; r++)
            hv[r] = *(const float4*)&s_h[w][r][k0];
        #pragma unroll
        for (int kk = 0; kk < 4; kk++) {
            float wvv[9];
            #pragma unroll
            for (int c = 0; c < 9; c++) wvv[c] = wa2_w[(k0 + kk) * NF + fcl[c]];
            #pragma unroll
            for (int r = 0; r < RPW; r++) {
                float t = ((const float*)&hv[r])[kk];
                #pragma unroll
                for (int c = 0; c < 9; c++) acc_l[r][c] += t * wvv[c];
            }
        }
    }

    // ---- phase 5: softmax, attention write, weighted sum, bias, q_total ----
    float wb2b0 = wb2_b[0];
    for (int r = 0; r < RPW; r++) {
        int row = r0 + r;
        float m = -3.0e38f;
        #pragma unroll
        for (int c = 0; c < 9; c++)
            if (c < 8 || lane < 16) m = fmaxf(m, acc_l[r][c]);
        #pragma unroll
        for (int off = 1; off < 64; off <<= 1) m = fmaxf(m, __shfl_xor(m, off, 64));

        float e[9];
        float s = 0.f;
        #pragma unroll
        for (int c = 0; c < 9; c++) {
            e[c] = (c < 8 || lane < 16) ? __expf(acc_l[r][c] - m) : 0.f;
            s += e[c];
        }
        #pragma unroll
        for (int off = 1; off < 64; off <<= 1) s += __shfl_xor(s, off, 64);
        float inv = 1.f / s;

        float wsum = 0.f;
        #pragma unroll
        for (int c = 0; c < 9; c++) {
            if (c < 8 || lane < 16) {
                int f = c * 64 + lane;
                float a = e[c] * inv;
                attn_out[(size_t)row * NF + f] = a;
                wsum += a * shape_out[(size_t)row * NF + f];
            }
        }
        #pragma unroll
        for (int off = 1; off < 64; off <<= 1) wsum += __shfl_xor(wsum, off, 64);
        if (lane == 0) q_total[row] = wsum + qb[r] + wb2b0;
    }
}

extern "C" void kernel_launch(void* const* d_in, const int* in_sizes, int n_in,
                              void* d_out, int out_size, void* d_ws, size_t ws_size,
                              hipStream_t stream) {
    const float* q     = (const float*)d_in[0];
    const float* state = (const float*)d_in[1];
    const float* sem   = (const float*)d_in[2];
    const float* w1_1  = (const float*)d_in[3];
    const float* b1_1  = (const float*)d_in[4];
    const float* w2_1  = (const float*)d_in[5];
    const float* b2_1  = (const float*)d_in[6];
    const float* w3_1  = (const float*)d_in[7];
    const float* b3_1  = (const float*)d_in[8];
    const float* w1_2  = (const float*)d_in[9];
    const float* b1_2  = (const float*)d_in[10];
    const float* w2_2  = (const float*)d_in[11];
    const float* b2_2  = (const float*)d_in[12];
    const float* w3_2  = (const float*)d_in[13];
    const float* b3_2  = (const float*)d_in[14];
    const float* ws_w  = (const float*)d_in[15];
    const float* ws_b  = (const float*)d_in[16];
    const float* wz_w  = (const float*)d_in[17];
    const float* wz_b  = (const float*)d_in[18];
    const float* wa1_w = (const float*)d_in[19];
    const float* wa1_b = (const float*)d_in[20];
    const float* wa2_w = (const float*)d_in[21];
    const float* wa2_b = (const float*)d_in[22];
    const float* wb1_w = (const float*)d_in[23];
    const float* wb1_b = (const float*)d_in[24];
    const float* wb2_w = (const float*)d_in[25];
    const float* wb2_b = (const float*)d_in[26];

    int B = in_sizes[0] / NAG;

    float* out_q    = (float*)d_out;                 // [B]
    float* out_attn = out_q + B;                     // [B, NF]
    float* out_shp  = out_attn + (size_t)B * NF;     // [B, NF]

    dim3 g1((NF + 63) / 64, B / ROWS1);
    shape_kernel<<<g1, 64, 0, stream>>>(q,
        w1_1, b1_1, w2_1, b2_1, w3_1, b3_1,
        w1_2, b1_2, w2_2, b2_2, w3_2, b3_2,
        out_shp, B);

    enc_kernel<<<B / (4 * RPW), 256, 0, stream>>>(state, sem,
        ws_w, ws_b, wz_w, wz_b, wa1_w, wa1_b, wa2_w, wa2_b,
        wb1_w, wb1_b, wb2_w, wb2_b,
        out_shp, out_q, out_attn, B);
}

// Round 2
// 405.885 us; speedup vs baseline: 1.8500x; 1.8500x over previous
//
#include <hip/hip_runtime.h>
#include <cstdint>
#include <cstddef>

#define NAG 32
#define N1C 32
#define N2C 496
#define NF 528
#define HD 64
#define SD 512

typedef __attribute__((ext_vector_type(8))) short bf16x8;
typedef __attribute__((ext_vector_type(4))) float f32x4;
#define MFMA16(a, b, c) __builtin_amdgcn_mfma_f32_16x16x32_bf16(a, b, c, 0, 0, 0)

__device__ __forceinline__ unsigned short f2bf(float f) {
    unsigned int u = __float_as_uint(f);
    u += 0x7fffu + ((u >> 16) & 1u);
    return (unsigned short)(u >> 16);
}
__device__ __forceinline__ unsigned int pack2(float a, float b) {
    return (unsigned int)f2bf(a) | ((unsigned int)f2bf(b) << 16);
}
__device__ __forceinline__ float elu_f(float x) {
    return x > 0.f ? x : (__expf(x) - 1.f);
}

// ---- d_ws layout (ushort/bf16): wsT[64][512], wb1T[64][512], wzT[64][512],
//      wa1T[64][128], wa2T[528][64]
#define OFF_WST   0
#define OFF_WB1T  32768
#define OFF_WZT   65536
#define OFF_WA1T  98304
#define OFF_WA2T  106496
#define PREP_TOT  140288

// ---------------- Kernel 0: weight transpose + bf16 convert ----------------
__global__ __launch_bounds__(256) void prep_kernel(
    const float* __restrict__ ws_w, const float* __restrict__ wb1_w,
    const float* __restrict__ wz_w, const float* __restrict__ wa1_w,
    const float* __restrict__ wa2_w, unsigned short* __restrict__ ws)
{
    int i = blockIdx.x * 256 + threadIdx.x;
    if (i >= PREP_TOT) return;
    float v;
    if (i < OFF_WB1T) {
        int j = i - OFF_WST; int n = j >> 9, k = j & 511;
        v = ws_w[k * 64 + n];
    } else if (i < OFF_WZT) {
        int j = i - OFF_WB1T; int n = j >> 9, k = j & 511;
        v = wb1_w[k * 64 + n];
    } else if (i < OFF_WA1T) {
        int j = i - OFF_WZT; int n = j >> 9, k = j & 511;
        v = wz_w[k * 64 + n];
    } else if (i < OFF_WA2T) {
        int j = i - OFF_WA1T; int n = j >> 7, k = j & 127;
        v = wa1_w[k * 64 + n];
    } else {
        int j = i - OFF_WA2T; int n = j >> 6, k = j & 63;
        v = wa2_w[k * NF + n];
    }
    ws[i] = f2bf(v);
}

// ---------------- Kernel 1: shape functions ----------------
// 576 threads (9 waves): lane -> function f (coalesced writes).
// q tile staged in LDS; rows looped with unroll for ILP.
#define SROWS 64
__global__ __launch_bounds__(576) void shape_kernel(
    const float* __restrict__ q,
    const float* __restrict__ w1_1, const float* __restrict__ b1_1,
    const float* __restrict__ w2_1, const float* __restrict__ b2_1,
    const float* __restrict__ w3_1, const float* __restrict__ b3_1,
    const float* __restrict__ w1_2, const float* __restrict__ b1_2,
    const float* __restrict__ w2_2, const float* __restrict__ b2_2,
    const float* __restrict__ w3_2, const float* __restrict__ b3_2,
    float* __restrict__ shape_out, int B)
{
    __shared__ float qs[SROWS][NAG];

    int tid = threadIdx.x;
    int f = tid;
    bool valid = f < NF;
    int fe = valid ? f : (NF - 1);

    float w1a[8], w1b[8], b1v[8], w2v[32], b2v[4], w3v[4], b3v;
    int pi, pj;
    if (fe < N1C) {
        int n = fe;
        pi = n; pj = n;
        #pragma unroll
        for (int k = 0; k < 8; k++) { w1a[k] = fabsf(w1_1[n*8+k]); w1b[k] = 0.f; b1v[k] = b1_1[n*8+k]; }
        #pragma unroll
        for (int t = 0; t < 32; t++) w2v[t] = fabsf(w2_1[n*32+t]);
        #pragma unroll
        for (int j = 0; j < 4; j++) { b2v[j] = b2_1[n*4+j]; w3v[j] = fabsf(w3_1[n*4+j]); }
        b3v = b3_1[n];
    } else {
        int n = fe - N1C;
        int p = n, i = 0, c = NAG - 1;
        while (p >= c) { p -= c; c--; i++; }
        pi = i; pj = i + 1 + p;
        #pragma unroll
        for (int k = 0; k < 8; k++) { w1a[k] = fabsf(w1_2[n*16+k]); w1b[k] = fabsf(w1_2[n*16+8+k]); b1v[k] = b1_2[n*8+k]; }
        #pragma unroll
        for (int t = 0; t < 32; t++) w2v[t] = fabsf(w2_2[n*32+t]);
        #pragma unroll
        for (int j = 0; j < 4; j++) { b2v[j] = b2_2[n*4+j]; w3v[j] = fabsf(w3_2[n*4+j]); }
        b3v = b3_2[n];
    }

    int row0 = blockIdx.x * SROWS;
    if (tid < 512) {
        float4 v = *(const float4*)&q[(size_t)row0 * NAG + tid * 4];
        *(float4*)&((float*)qs)[tid * 4] = v;
    }
    __syncthreads();

    #pragma unroll 4
    for (int rr = 0; rr < SROWS; rr++) {
        float qi = qs[rr][pi];
        float qj = qs[rr][pj];
        float h1[8];
        #pragma unroll
        for (int k = 0; k < 8; k++) h1[k] = elu_f(w1a[k]*qi + w1b[k]*qj + b1v[k]);
        float h2[4];
        #pragma unroll
        for (int j = 0; j < 4; j++) {
            float a = b2v[j];
            #pragma unroll
            for (int k = 0; k < 8; k++) a += h1[k] * w2v[k*4 + j];
            h2[j] = elu_f(a);
        }
        float fv = b3v;
        #pragma unroll
        for (int j = 0; j < 4; j++) fv += h2[j] * w3v[j];
        if (valid) shape_out[(size_t)(row0 + rr) * NF + f] = fv;
    }
}

// ---------------- Kernel 2: MFMA encoder + attention + combine ----------------
// 64 rows/block, 4 waves; wave w owns rows [16w,16w+16) end-to-end.
// MFMA 16x16x32 bf16. A staged fp32->bf16 in LDS; B from prepped bf16 Wt[n][k].
// A-frag: lane holds A[m=lane&15][k=8*(lane>>4)+j]; D: row=quad*4+reg, col=lane&15.
#define RB 64
__global__ __launch_bounds__(256, 2) void enc_mfma(
    const float* __restrict__ state,
    const float* __restrict__ sem,
    const unsigned short* __restrict__ wsbuf,
    const float* __restrict__ ws_b, const float* __restrict__ wz_b,
    const float* __restrict__ wa1_b, const float* __restrict__ wa2_b,
    const float* __restrict__ wb1_b, const float* __restrict__ wb2_w,
    const float* __restrict__ wb2_b,
    const float* __restrict__ shape_out,
    float* __restrict__ q_total,
    float* __restrict__ attn_out)
{
    __shared__ unsigned short sA[RB][72];     // A chunk (Kc=64), padded
    __shared__ unsigned short sComb[RB][136]; // [relu(C1)|relu(C3)], padded
    __shared__ unsigned short sH[RB][72];     // relu(C4), padded

    const unsigned short* wsT  = wsbuf + OFF_WST;
    const unsigned short* wb1T = wsbuf + OFF_WB1T;
    const unsigned short* wzT  = wsbuf + OFF_WZT;
    const unsigned short* wa1T = wsbuf + OFF_WA1T;
    const unsigned short* wa2T = wsbuf + OFF_WA2T;

    int tid  = threadIdx.x;
    int lane = tid & 63;
    int w    = tid >> 6;
    int col  = lane & 15;
    int quad = lane >> 4;
    int r0   = blockIdx.x * RB;
    int rowt = w * 16;

    f32x4 accS[4], accB[4], accZ[4];
    #pragma unroll
    for (int ct = 0; ct < 4; ct++) {
        accS[ct] = (f32x4){0.f,0.f,0.f,0.f};
        accB[ct] = (f32x4){0.f,0.f,0.f,0.f};
        accZ[ct] = (f32x4){0.f,0.f,0.f,0.f};
    }

    // ---- state -> C1 (ws), C2 (wb1) ----
    for (int chunk = 0; chunk < 8; chunk++) {
        __syncthreads();
        #pragma unroll
        for (int i = 0; i < 4; i++) {
            int idx = i * 256 + tid;           // float4 index 0..1023
            int sr = idx >> 4;
            int sc = (idx & 15) << 2;
            float4 v = *(const float4*)&state[(size_t)(r0 + sr) * SD + chunk * 64 + sc];
            uint2 p; p.x = pack2(v.x, v.y); p.y = pack2(v.z, v.w);
            *(uint2*)&sA[sr][sc] = p;
        }
        __syncthreads();
        #pragma unroll
        for (int ks = 0; ks < 2; ks++) {
            bf16x8 a = *(const bf16x8*)&sA[rowt + col][ks * 32 + quad * 8];
            int wof = chunk * 64 + ks * 32 + quad * 8;
            #pragma unroll
            for (int ct = 0; ct < 4; ct++) {
                bf16x8 bS = *(const bf16x8*)&wsT [(ct * 16 + col) * SD + wof];
                bf16x8 bB = *(const bf16x8*)&wb1T[(ct * 16 + col) * SD + wof];
                accS[ct] = MFMA16(a, bS, accS[ct]);
                accB[ct] = MFMA16(a, bB, accB[ct]);
            }
        }
    }

    // ---- sem -> C3 (wz) ----
    for (int chunk = 0; chunk < 8; chunk++) {
        __syncthreads();
        #pragma unroll
        for (int i = 0; i < 4; i++) {
            int idx = i * 256 + tid;
            int sr = idx >> 4;
            int sc = (idx & 15) << 2;
            float4 v = *(const float4*)&sem[(size_t)(r0 + sr) * SD + chunk * 64 + sc];
            uint2 p; p.x = pack2(v.x, v.y); p.y = pack2(v.z, v.w);
            *(uint2*)&sA[sr][sc] = p;
        }
        __syncthreads();
        #pragma unroll
        for (int ks = 0; ks < 2; ks++) {
            bf16x8 a = *(const bf16x8*)&sA[rowt + col][ks * 32 + quad * 8];
            int wof = chunk * 64 + ks * 32 + quad * 8;
            #pragma unroll
            for (int ct = 0; ct < 4; ct++) {
                bf16x8 bZ = *(const bf16x8*)&wzT[(ct * 16 + col) * SD + wof];
                accZ[ct] = MFMA16(a, bZ, accZ[ct]);
            }
        }
    }

    // ---- comb = [relu(C1+ws_b) | relu(C3+wz_b)] (own rows only -> no barrier) ----
    #pragma unroll
    for (int ct = 0; ct < 4; ct++) {
        float bs = ws_b[ct * 16 + col];
        float bz = wz_b[ct * 16 + col];
        #pragma unroll
        for (int reg = 0; reg < 4; reg++) {
            int rr = rowt + quad * 4 + reg;
            sComb[rr][ct * 16 + col]      = f2bf(fmaxf(accS[ct][reg] + bs, 0.f));
            sComb[rr][64 + ct * 16 + col] = f2bf(fmaxf(accZ[ct][reg] + bz, 0.f));
        }
    }

    // ---- bias head: qb = relu(C2+wb1_b) @ wb2_w ----
    float qbv[4];
    #pragma unroll
    for (int reg = 0; reg < 4; reg++) {
        float p = 0.f;
        #pragma unroll
        for (int ct = 0; ct < 4; ct++)
            p += fmaxf(accB[ct][reg] + wb1_b[ct * 16 + col], 0.f) * wb2_w[ct * 16 + col];
        #pragma unroll
        for (int m = 1; m < 16; m <<= 1) p += __shfl_xor(p, m, 64);
        qbv[reg] = p;
    }

    // ---- C4 = comb @ wa1 ----
    f32x4 accH[4];
    #pragma unroll
    for (int ct = 0; ct < 4; ct++) accH[ct] = (f32x4){0.f,0.f,0.f,0.f};
    #pragma unroll
    for (int ks = 0; ks < 4; ks++) {
        bf16x8 a = *(const bf16x8*)&sComb[rowt + col][ks * 32 + quad * 8];
        #pragma unroll
        for (int ct = 0; ct < 4; ct++) {
            bf16x8 b = *(const bf16x8*)&wa1T[(ct * 16 + col) * 128 + ks * 32 + quad * 8];
            accH[ct] = MFMA16(a, b, accH[ct]);
        }
    }
    #pragma unroll
    for (int ct = 0; ct < 4; ct++) {
        float bh = wa1_b[ct * 16 + col];
        #pragma unroll
        for (int reg = 0; reg < 4; reg++)
            sH[rowt + quad * 4 + reg][ct * 16 + col] = f2bf(fmaxf(accH[ct][reg] + bh, 0.f));
    }

    bf16x8 ha0 = *(const bf16x8*)&sH[rowt + col][quad * 8];
    bf16x8 ha1 = *(const bf16x8*)&sH[rowt + col][32 + quad * 8];

    // ---- pass 1: sum of exp(logits), weighted sum with shape_out ----
    float sAcc[4] = {0.f,0.f,0.f,0.f};
    float wAcc[4] = {0.f,0.f,0.f,0.f};
    for (int nt = 0; nt < 33; nt++) {
        f32x4 acc = (f32x4){0.f,0.f,0.f,0.f};
        const unsigned short* wp = &wa2T[(nt * 16 + col) * 64 + quad * 8];
        acc = MFMA16(ha0, *(const bf16x8*)wp, acc);
        acc = MFMA16(ha1, *(const bf16x8*)(wp + 32), acc);
        float lb = wa2_b[nt * 16 + col];
        #pragma unroll
        for (int reg = 0; reg < 4; reg++) {
            float e = __expf(acc[reg] + lb);
            sAcc[reg] += e;
            wAcc[reg] += e * shape_out[(size_t)(r0 + rowt + quad * 4 + reg) * NF + nt * 16 + col];
        }
    }
    float inv[4];
    #pragma unroll
    for (int reg = 0; reg < 4; reg++) {
        float s = sAcc[reg], ww = wAcc[reg];
        #pragma unroll
        for (int m = 1; m < 16; m <<= 1) { s += __shfl_xor(s, m, 64); ww += __shfl_xor(ww, m, 64); }
        inv[reg] = 1.f / s;
        if (col == 0)
            q_total[r0 + rowt + quad * 4 + reg] = ww * inv[reg] + qbv[reg] + wb2_b[0];
    }

    // ---- pass 2: write normalized attention ----
    for (int nt = 0; nt < 33; nt++) {
        f32x4 acc = (f32x4){0.f,0.f,0.f,0.f};
        const unsigned short* wp = &wa2T[(nt * 16 + col) * 64 + quad * 8];
        acc = MFMA16(ha0, *(const bf16x8*)wp, acc);
        acc = MFMA16(ha1, *(const bf16x8*)(wp + 32), acc);
        float lb = wa2_b[nt * 16 + col];
        #pragma unroll
        for (int reg = 0; reg < 4; reg++) {
            float e = __expf(acc[reg] + lb);
            attn_out[(size_t)(r0 + rowt + quad * 4 + reg) * NF + nt * 16 + col] = e * inv[reg];
        }
    }
}

extern "C" void kernel_launch(void* const* d_in, const int* in_sizes, int n_in,
                              void* d_out, int out_size, void* d_ws, size_t ws_size,
                              hipStream_t stream) {
    const float* q     = (const float*)d_in[0];
    const float* state = (const float*)d_in[1];
    const float* sem   = (const float*)d_in[2];
    const float* w1_1  = (const float*)d_in[3];
    const float* b1_1  = (const float*)d_in[4];
    const float* w2_1  = (const float*)d_in[5];
    const float* b2_1  = (const float*)d_in[6];
    const float* w3_1  = (const float*)d_in[7];
    const float* b3_1  = (const float*)d_in[8];
    const float* w1_2  = (const float*)d_in[9];
    const float* b1_2  = (const float*)d_in[10];
    const float* w2_2  = (const float*)d_in[11];
    const float* b2_2  = (const float*)d_in[12];
    const float* w3_2  = (const float*)d_in[13];
    const float* b3_2  = (const float*)d_in[14];
    const float* ws_w  = (const float*)d_in[15];
    const float* ws_b  = (const float*)d_in[16];
    const float* wz_w  = (const float*)d_in[17];
    const float* wz_b  = (const float*)d_in[18];
    const float* wa1_w = (const float*)d_in[19];
    const float* wa1_b = (const float*)d_in[20];
    const float* wa2_w = (const float*)d_in[21];
    const float* wa2_b = (const float*)d_in[22];
    const float* wb1_w = (const float*)d_in[23];
    const float* wb1_b = (const float*)d_in[24];
    const float* wb2_w = (const float*)d_in[25];
    const float* wb2_b = (const float*)d_in[26];

    int B = in_sizes[0] / NAG;

    float* out_q    = (float*)d_out;                 // [B]
    float* out_attn = out_q + B;                     // [B, NF]
    float* out_shp  = out_attn + (size_t)B * NF;     // [B, NF]

    unsigned short* wsbuf = (unsigned short*)d_ws;

    prep_kernel<<<(PREP_TOT + 255) / 256, 256, 0, stream>>>(
        ws_w, wb1_w, wz_w, wa1_w, wa2_w, wsbuf);

    shape_kernel<<<B / SROWS, 576, 0, stream>>>(q,
        w1_1, b1_1, w2_1, b2_1, w3_1, b3_1,
        w1_2, b1_2, w2_2, b2_2, w3_2, b3_2,
        out_shp, B);

    enc_mfma<<<B / RB, 256, 0, stream>>>(state, sem, wsbuf,
        ws_b, wz_b, wa1_b, wa2_b, wb1_b, wb2_w, wb2_b,
        out_shp, out_q, out_attn);
}